// Round 1
// baseline (2493.380 us; speedup 1.0000x reference)
//
#include <hip/hip_runtime.h>

// SLULatticeRNN: B=32, S=256, K=3, D=H=512, 4H=2048, V=50257, L=128.
// Plan: prep (X=emb[inputs]->bf16, Wih->bf16, bias) ; gemm_gx (bf16 MFMA, gates_x = X@Wih^T+b) ;
// recur (32 persistent blocks, h-slice of 16 per block, per-step device-scope barrier, Whh slice in LDS) ;
// pool_lin. Pooling max kept in registers inside recur.

#define BB 32
#define SS 256
#define KKK 3
#define DD 512
#define HH 512
#define G4 2048
#define LL 128

typedef __attribute__((ext_vector_type(4))) float f32x4;
typedef __attribute__((ext_vector_type(8))) short bf16x8;
typedef __attribute__((ext_vector_type(8))) unsigned short ushort8;

__device__ __forceinline__ float bf2f(unsigned short u){
  unsigned int x = ((unsigned int)u) << 16;
  return __builtin_bit_cast(float, x);
}
__device__ __forceinline__ unsigned short f2bf(float f){
  unsigned int x = __builtin_bit_cast(unsigned int, f);
  x = x + 0x7fffu + ((x >> 16) & 1u);
  return (unsigned short)(x >> 16);
}
__device__ __forceinline__ float sigm(float x){ return 1.0f / (1.0f + __expf(-x)); }
__device__ __forceinline__ float tanh_(float x){
  float ax = fabsf(x);
  float e = __expf(-2.0f * ax);
  float r = (1.0f - e) / (1.0f + e);
  return x < 0.0f ? -r : r;
}
__device__ __forceinline__ void glds16(const void* g, void* lds){
  __builtin_amdgcn_global_load_lds((const __attribute__((address_space(1))) unsigned int*)g,
                                   (__attribute__((address_space(3))) unsigned int*)lds, 16, 0, 0);
}

// ---------------- prep: X gather->bf16, Wih->bf16, bias ----------------
__global__ __launch_bounds__(256) void prep_kernel(
    const int* __restrict__ inputs, const float* __restrict__ emb,
    const float* __restrict__ Wih, const float* __restrict__ bih, const float* __restrict__ bhh,
    unsigned short* __restrict__ Xb, unsigned short* __restrict__ Wihb, float* __restrict__ bias)
{
  int blk = blockIdx.x, tid = threadIdx.x;
  if (blk < 512){
    int row = blk * 16 + (tid >> 4);       // m = t*32+b
    int d0 = (tid & 15) * 32;
    int b = row & 31, t = row >> 5;
    int tok = inputs[b * SS + t];
    const float* src = emb + (size_t)tok * DD + d0;
    unsigned short* dst = Xb + (size_t)row * DD + d0;
    #pragma unroll
    for (int j = 0; j < 32; j += 4){
      float4 v = *(const float4*)(src + j);
      uint2 o;
      o.x = (unsigned)f2bf(v.x) | ((unsigned)f2bf(v.y) << 16);
      o.y = (unsigned)f2bf(v.z) | ((unsigned)f2bf(v.w) << 16);
      *(uint2*)(dst + j) = o;
    }
  } else if (blk < 640){
    int row = (blk - 512) * 16 + (tid >> 4);
    int d0 = (tid & 15) * 32;
    const float* src = Wih + (size_t)row * DD + d0;
    unsigned short* dst = Wihb + (size_t)row * DD + d0;
    #pragma unroll
    for (int j = 0; j < 32; j += 4){
      float4 v = *(const float4*)(src + j);
      uint2 o;
      o.x = (unsigned)f2bf(v.x) | ((unsigned)f2bf(v.y) << 16);
      o.y = (unsigned)f2bf(v.z) | ((unsigned)f2bf(v.w) << 16);
      *(uint2*)(dst + j) = o;
    }
  } else {
    for (int n = tid; n < G4; n += 256) bias[n] = bih[n] + bhh[n];
  }
}

// ---------------- gemm_gx: gates_x[m][n] = X[m]·Wih[n] + bias[n], bf16 out ----------------
__global__ __launch_bounds__(256) void gemm_gx(
    const unsigned short* __restrict__ Xb, const unsigned short* __restrict__ Wihb,
    const float* __restrict__ bias, unsigned short* __restrict__ gx)
{
  __shared__ unsigned short As[128 * 32];
  __shared__ unsigned short Bs[128 * 32];
  const int tid = threadIdx.x;
  const int lane = tid & 63, wid = tid >> 6;
  const int m0 = blockIdx.x * 128, n0 = blockIdx.y * 128;
  const int wm = wid & 1, wn = wid >> 1;
  f32x4 acc[4][4];
  #pragma unroll
  for (int i = 0; i < 4; i++)
    #pragma unroll
    for (int j = 0; j < 4; j++)
      acc[i][j] = (f32x4){0.f, 0.f, 0.f, 0.f};

  for (int kk = 0; kk < DD; kk += 32){
    #pragma unroll
    for (int r = 0; r < 2; r++){
      int q = r * 256 + wid * 64 + lane;
      int row = q >> 2, seg = q & 3;
      glds16(Xb   + (size_t)(m0 + row) * DD + kk + seg * 8, As + (size_t)(r * 256 + wid * 64) * 8);
      glds16(Wihb + (size_t)(n0 + row) * DD + kk + seg * 8, Bs + (size_t)(r * 256 + wid * 64) * 8);
    }
    __syncthreads();
    bf16x8 af[4], bfv[4];
    #pragma unroll
    for (int i = 0; i < 4; i++){
      int ra = wm * 64 + i * 16 + (lane & 15);
      af[i] = *(const bf16x8*)(As + ra * 32 + (lane >> 4) * 8);
      int rb = wn * 64 + i * 16 + (lane & 15);
      bfv[i] = *(const bf16x8*)(Bs + rb * 32 + (lane >> 4) * 8);
    }
    #pragma unroll
    for (int i = 0; i < 4; i++)
      #pragma unroll
      for (int j = 0; j < 4; j++)
        acc[i][j] = __builtin_amdgcn_mfma_f32_16x16x32_bf16(af[i], bfv[j], acc[i][j], 0, 0, 0);
    __syncthreads();
  }
  #pragma unroll
  for (int j = 0; j < 4; j++){
    int ncol = n0 + wn * 64 + j * 16 + (lane & 15);
    float bv = bias[ncol];
    #pragma unroll
    for (int i = 0; i < 4; i++){
      int mbase = m0 + wm * 64 + i * 16 + (lane >> 4) * 4;
      #pragma unroll
      for (int r = 0; r < 4; r++)
        gx[(size_t)(mbase + r) * G4 + ncol] = f2bf(acc[i][j][r] + bv);
    }
  }
}

// ---------------- recur: 32 persistent blocks, one h-slice (16) each ----------------
// h_bf layout:  [t][slice=blk][b][16]  bf16 (slice region 1KB, single-writer)
// c_hist layout:[t][slice=blk][b][16]  fp32 (block-private)
__global__ __launch_bounds__(256) void recur_kernel(
    const int* __restrict__ prev_idx, const float* __restrict__ prev_w,
    const float* __restrict__ Whh, const int* __restrict__ positions,
    const unsigned short* __restrict__ gx, unsigned short* __restrict__ h_bf,
    float* __restrict__ c_hist, float* __restrict__ pooled, unsigned int* cnt)
{
  extern __shared__ char smem[];
  // [0,65536): WhhL [64][512] bf16, swizzled; [65536,98304): hA [32][512] bf16, swizzled
  char* hA = smem + 65536;
  float* gex = (float*)(smem + 65536 + 32768);            // [32][64]
  float* wst = (float*)(smem + 65536 + 32768 + 8192);     // [32][3]
  int*   ist = (int*)  (smem + 65536 + 32768 + 8192 + 384);

  const int tid = threadIdx.x, bid = blockIdx.x;
  const int lane = tid & 63, wid = tid >> 6;
  const int hs0 = bid * 16;

  // load Whh slice (rows: [gate][hl]) -> LDS bf16, XOR-swizzled
  for (int e = tid; e < 64 * 128; e += 256){
    int r = e >> 7, c4 = e & 127;
    int grow = (r >> 4) * HH + hs0 + (r & 15);
    float4 v = *(const float4*)(Whh + (size_t)grow * HH + c4 * 4);
    uint2 o;
    o.x = (unsigned)f2bf(v.x) | ((unsigned)f2bf(v.y) << 16);
    o.y = (unsigned)f2bf(v.z) | ((unsigned)f2bf(v.w) << 16);
    int colb = c4 * 8;
    int off = (r << 10) + colb;
    off ^= (((r ^ (colb >> 7)) & 7) << 4);
    *(uint2*)(smem + off) = o;
  }

  const int b_my = tid >> 3;
  const int hl0 = (tid & 7) * 2;
  const int st = positions[b_my * 2], en = positions[b_my * 2 + 1];
  float pm0 = -1e30f, pm1 = -1e30f;

  __syncthreads();

  for (int t = 0; t < SS; t++){
    if (t > 0){
      if (tid == 0){
        while (__hip_atomic_load(cnt + (t - 1), __ATOMIC_RELAXED, __HIP_MEMORY_SCOPE_AGENT) < 32u)
          __builtin_amdgcn_s_sleep(2);
      }
      __syncthreads();
      __builtin_amdgcn_fence(__ATOMIC_ACQUIRE, "agent");
      if (tid < 96){
        int b = tid / 3, k = tid - b * 3;
        ist[tid] = prev_idx[b * (SS * KKK) + t * KKK + k];
        wst[tid] = prev_w [b * (SS * KKK) + t * KKK + k];
      }
      __syncthreads();
      { // gather h~ -> hA (bf16, swizzled)
        int b = tid >> 3;
        int h0 = (tid & 7) * 64;
        float w0 = wst[b * 3], w1 = wst[b * 3 + 1], w2 = wst[b * 3 + 2];
        int i0 = ist[b * 3], i1 = ist[b * 3 + 1], i2 = ist[b * 3 + 2];
        #pragma unroll
        for (int half = 0; half < 2; half++){
          int hh = h0 + half * 32;
          int s0 = hh >> 4;
          int base0 = ((i0 * BB + s0) * BB + b) * 16;
          int base1 = ((i1 * BB + s0) * BB + b) * 16;
          int base2 = ((i2 * BB + s0) * BB + b) * 16;
          ushort8 A0[4], A1[4], A2[4];
          #pragma unroll
          for (int c = 0; c < 4; c++){
            int off = (c >> 1) * (BB * 16) + (c & 1) * 8;
            A0[c] = *(const ushort8*)(h_bf + base0 + off);
            A1[c] = *(const ushort8*)(h_bf + base1 + off);
            A2[c] = *(const ushort8*)(h_bf + base2 + off);
          }
          #pragma unroll
          for (int c = 0; c < 4; c++){
            unsigned int pk[4];
            #pragma unroll
            for (int u = 0; u < 4; u++){
              float lo = w0 * bf2f(A0[c][2*u])   + w1 * bf2f(A1[c][2*u])   + w2 * bf2f(A2[c][2*u]);
              float hi = w0 * bf2f(A0[c][2*u+1]) + w1 * bf2f(A1[c][2*u+1]) + w2 * bf2f(A2[c][2*u+1]);
              pk[u] = (unsigned)f2bf(lo) | ((unsigned)f2bf(hi) << 16);
            }
            int colb = (hh + 8 * c) * 2;
            int off = (b << 10) + colb;
            off ^= (((b ^ (colb >> 7)) & 7) << 4);
            *(uint4*)(hA + off) = *(uint4*)pk;
          }
        }
      }
    }
    __syncthreads();
    if (t > 0){
      // MFMA: wave wid owns gate rows [wid*16, wid*16+16); A rows = batches
      f32x4 acc0 = {0.f,0.f,0.f,0.f}, acc1 = {0.f,0.f,0.f,0.f};
      const int rB = wid * 16 + (lane & 15);
      const int rA0 = lane & 15, rA1 = 16 + (lane & 15);
      const int kb = (lane >> 4) * 16;
      #pragma unroll
      for (int kc = 0; kc < 16; kc++){
        int colb = kc * 64 + kb;
        int sw = (colb >> 7) & 7;
        int offB  = ((rB  << 10) + colb) ^ (((rB  ^ sw) & 7) << 4);
        int offA0 = ((rA0 << 10) + colb) ^ (((rA0 ^ sw) & 7) << 4);
        int offA1 = ((rA1 << 10) + colb) ^ (((rA1 ^ sw) & 7) << 4);
        bf16x8 bv = *(const bf16x8*)(smem + offB);
        bf16x8 a0 = *(const bf16x8*)(hA + offA0);
        bf16x8 a1 = *(const bf16x8*)(hA + offA1);
        acc0 = __builtin_amdgcn_mfma_f32_16x16x32_bf16(a0, bv, acc0, 0, 0, 0);
        acc1 = __builtin_amdgcn_mfma_f32_16x16x32_bf16(a1, bv, acc1, 0, 0, 0);
      }
      int cl = wid * 16 + (lane & 15);
      #pragma unroll
      for (int j = 0; j < 4; j++){
        int br = (lane >> 4) * 4 + j;
        gex[br * 64 + cl] = acc0[j];
        gex[(br + 16) * 64 + cl] = acc1[j];
      }
    }
    __syncthreads();
    { // elementwise LSTM cell for this block's slice
      int b = b_my;
      const unsigned short* gxr = gx + ((size_t)t * BB + b) * G4 + hs0;
      float w0 = 0.f, w1 = 0.f, w2 = 0.f; int i0 = 0, i1 = 0, i2 = 0;
      if (t > 0){
        w0 = wst[b*3]; w1 = wst[b*3+1]; w2 = wst[b*3+2];
        i0 = ist[b*3]; i1 = ist[b*3+1]; i2 = ist[b*3+2];
      }
      #pragma unroll
      for (int p = 0; p < 2; p++){
        int hl = hl0 + p;
        float gi = bf2f(gxr[hl]);
        float gf = bf2f(gxr[512 + hl]);
        float gg = bf2f(gxr[1024 + hl]);
        float go = bf2f(gxr[1536 + hl]);
        float co = 0.f;
        if (t > 0){
          gi += gex[b * 64 + hl];
          gf += gex[b * 64 + 16 + hl];
          gg += gex[b * 64 + 32 + hl];
          go += gex[b * 64 + 48 + hl];
          co = w0 * c_hist[((size_t)(i0 * BB + bid) * BB + b) * 16 + hl]
             + w1 * c_hist[((size_t)(i1 * BB + bid) * BB + b) * 16 + hl]
             + w2 * c_hist[((size_t)(i2 * BB + bid) * BB + b) * 16 + hl];
        }
        float iS = sigm(gi), fS = sigm(gf), gT = tanh_(gg), oS = sigm(go);
        float cn = fS * co + iS * gT;
        float hn = oS * tanh_(cn);
        c_hist[((size_t)(t * BB + bid) * BB + b) * 16 + hl] = cn;
        h_bf [((size_t)(t * BB + bid) * BB + b) * 16 + hl] = f2bf(hn);
        if (t >= st && t < en){ if (p == 0) pm0 = fmaxf(pm0, hn); else pm1 = fmaxf(pm1, hn); }
      }
    }
    __syncthreads();   // drains vmcnt before barrier -> stores visible before release
    if (tid == 0)
      __hip_atomic_fetch_add(cnt + t, 1u, __ATOMIC_RELEASE, __HIP_MEMORY_SCOPE_AGENT);
  }
  pooled[b_my * HH + hs0 + hl0]     = (en > st && pm0 > -1e29f) ? pm0 : 0.f;
  pooled[b_my * HH + hs0 + hl0 + 1] = (en > st && pm1 > -1e29f) ? pm1 : 0.f;
}

// ---------------- pool_lin: out[b][l] = pooled[b]·W_lin[l] + b_lin[l] ----------------
__global__ __launch_bounds__(128) void pool_lin(
    const float* __restrict__ pooled, const float* __restrict__ W_lin,
    const float* __restrict__ b_lin, float* __restrict__ out)
{
  __shared__ float p[HH];
  int b = blockIdx.x, tid = threadIdx.x;
  *(float4*)&p[tid * 4] = *(const float4*)&pooled[(size_t)b * HH + tid * 4];
  __syncthreads();
  float acc = b_lin[tid];
  const float* wr = W_lin + (size_t)tid * HH;
  #pragma unroll 8
  for (int h = 0; h < HH; h += 4){
    float4 w = *(const float4*)(wr + h);
    acc += w.x * p[h] + w.y * p[h+1] + w.z * p[h+2] + w.w * p[h+3];
  }
  out[b * LL + tid] = acc;
}

extern "C" void kernel_launch(void* const* d_in, const int* in_sizes, int n_in,
                              void* d_out, int out_size, void* d_ws, size_t ws_size,
                              hipStream_t stream)
{
  (void)in_sizes; (void)n_in; (void)out_size; (void)ws_size;
  const int*   inputs    = (const int*)  d_in[0];
  const int*   positions = (const int*)  d_in[1];
  const int*   prev_idx  = (const int*)  d_in[2];
  const float* prev_w    = (const float*)d_in[3];
  const float* emb       = (const float*)d_in[4];
  const float* Wih       = (const float*)d_in[5];
  const float* Whh       = (const float*)d_in[6];
  const float* bih       = (const float*)d_in[7];
  const float* bhh       = (const float*)d_in[8];
  const float* W_lin     = (const float*)d_in[9];
  const float* b_lin     = (const float*)d_in[10];
  float* out = (float*)d_out;
  char* ws = (char*)d_ws;

  unsigned int*   cnt    = (unsigned int*)  ws;                 // 1024 B
  unsigned short* Xb     = (unsigned short*)(ws + 4096);        // 8 MB
  unsigned short* Wihb   = (unsigned short*)(ws + 8392704);     // 2 MB
  float*          bias   = (float*)         (ws + 10489856);    // 8 KB
  unsigned short* gx     = (unsigned short*)(ws + 10498048);    // 32 MB
  unsigned short* h_bf   = (unsigned short*)(ws + 44052480);    // 8 MB
  float*          c_hist = (float*)         (ws + 52441088);    // 16 MB
  float*          pooled = (float*)         (ws + 69218304);    // 64 KB  (total ~66.1 MB)

  hipMemsetAsync(cnt, 0, 1024, stream);
  prep_kernel<<<641, 256, 0, stream>>>(inputs, emb, Wih, bih, bhh, Xb, Wihb, bias);
  gemm_gx<<<dim3(64, 16), 256, 0, stream>>>(Xb, Wihb, bias, gx);
  hipFuncSetAttribute(reinterpret_cast<const void*>(recur_kernel),
                      hipFuncAttributeMaxDynamicSharedMemorySize, 107264);
  recur_kernel<<<32, 256, 107264, stream>>>(prev_idx, prev_w, Whh, positions, gx, h_bf, c_hist, pooled, cnt);
  pool_lin<<<32, 128, 0, stream>>>(pooled, W_lin, b_lin, out);
}

// Round 2
// 2293.738 us; speedup vs baseline: 1.0870x; 1.0870x over previous
//
#include <hip/hip_runtime.h>

// SLULatticeRNN: B=32, S=256, K=3, D=H=512, 4H=2048, L=128.
// Key fact: prev_idx gathers are WITHIN each batch -> batches independent.
// recur2: 2 groups x 16 batches; group = 8 blocks; block holds Whh slice
// (256 gate-rows x 512) in VGPRs as MFMA B-frags. Per-step exchange of 2KB
// h-slices via LLC using relaxed agent-scope dword atomics + tag counters.
// No cache-wide fences (no buffer_wbl2/inv), no global barrier.

#define BB 32
#define SS 256
#define KKK 3
#define DD 512
#define HH 512
#define G4 2048
#define LL 128
#define NG 2    // batch groups
#define GS 8    // slice blocks per group
#define NB 16   // batches per group
#define HSL 64  // h dims per slice block

typedef __attribute__((ext_vector_type(4))) float f32x4;
typedef __attribute__((ext_vector_type(8))) short bf16x8;

__device__ __forceinline__ float bfu(unsigned short u){
  return __builtin_bit_cast(float, (unsigned int)u << 16);
}
__device__ __forceinline__ float blo(unsigned int u){
  return __builtin_bit_cast(float, u << 16);
}
__device__ __forceinline__ float bhi(unsigned int u){
  return __builtin_bit_cast(float, u & 0xffff0000u);
}
__device__ __forceinline__ unsigned int f2bf(float f){
  unsigned int x = __builtin_bit_cast(unsigned int, f);
  x = x + 0x7fffu + ((x >> 16) & 1u);
  return x >> 16;
}
__device__ __forceinline__ float sigm(float x){ return 1.0f / (1.0f + __expf(-x)); }
__device__ __forceinline__ float tanh_(float x){
  float ax = fabsf(x);
  float e = __expf(-2.0f * ax);
  float r = (1.0f - e) / (1.0f + e);
  return x < 0.0f ? -r : r;
}
__device__ __forceinline__ void glds16(const void* g, void* lds){
  __builtin_amdgcn_global_load_lds((const __attribute__((address_space(1))) unsigned int*)g,
                                   (__attribute__((address_space(3))) unsigned int*)lds, 16, 0, 0);
}

// ---------------- prep: X gather->bf16, Wih->bf16, bias ----------------
__global__ __launch_bounds__(256) void prep_kernel(
    const int* __restrict__ inputs, const float* __restrict__ emb,
    const float* __restrict__ Wih, const float* __restrict__ bih, const float* __restrict__ bhh,
    unsigned short* __restrict__ Xb, unsigned short* __restrict__ Wihb, float* __restrict__ bias)
{
  int blk = blockIdx.x, tid = threadIdx.x;
  if (blk < 512){
    int row = blk * 16 + (tid >> 4);       // m = t*32+b
    int d0 = (tid & 15) * 32;
    int b = row & 31, t = row >> 5;
    int tok = inputs[b * SS + t];
    const float* src = emb + (size_t)tok * DD + d0;
    unsigned short* dst = Xb + (size_t)row * DD + d0;
    #pragma unroll
    for (int j = 0; j < 32; j += 4){
      float4 v = *(const float4*)(src + j);
      uint2 o;
      o.x = f2bf(v.x) | (f2bf(v.y) << 16);
      o.y = f2bf(v.z) | (f2bf(v.w) << 16);
      *(uint2*)(dst + j) = o;
    }
  } else if (blk < 640){
    int row = (blk - 512) * 16 + (tid >> 4);
    int d0 = (tid & 15) * 32;
    const float* src = Wih + (size_t)row * DD + d0;
    unsigned short* dst = Wihb + (size_t)row * DD + d0;
    #pragma unroll
    for (int j = 0; j < 32; j += 4){
      float4 v = *(const float4*)(src + j);
      uint2 o;
      o.x = f2bf(v.x) | (f2bf(v.y) << 16);
      o.y = f2bf(v.z) | (f2bf(v.w) << 16);
      *(uint2*)(dst + j) = o;
    }
  } else {
    for (int n = tid; n < G4; n += 256) bias[n] = bih[n] + bhh[n];
  }
}

// ---------------- gemm_gx: gates_x[m][n] = X[m]·Wih[n] + bias[n], bf16 out ----------------
__global__ __launch_bounds__(256) void gemm_gx(
    const unsigned short* __restrict__ Xb, const unsigned short* __restrict__ Wihb,
    const float* __restrict__ bias, unsigned short* __restrict__ gx)
{
  __shared__ unsigned short As[128 * 32];
  __shared__ unsigned short Bs[128 * 32];
  const int tid = threadIdx.x;
  const int lane = tid & 63, wid = tid >> 6;
  const int m0 = blockIdx.x * 128, n0 = blockIdx.y * 128;
  const int wm = wid & 1, wn = wid >> 1;
  f32x4 acc[4][4];
  #pragma unroll
  for (int i = 0; i < 4; i++)
    #pragma unroll
    for (int j = 0; j < 4; j++)
      acc[i][j] = (f32x4){0.f, 0.f, 0.f, 0.f};

  for (int kk = 0; kk < DD; kk += 32){
    #pragma unroll
    for (int r = 0; r < 2; r++){
      int q = r * 256 + wid * 64 + lane;
      int row = q >> 2, seg = q & 3;
      glds16(Xb   + (size_t)(m0 + row) * DD + kk + seg * 8, As + (size_t)(r * 256 + wid * 64) * 8);
      glds16(Wihb + (size_t)(n0 + row) * DD + kk + seg * 8, Bs + (size_t)(r * 256 + wid * 64) * 8);
    }
    __syncthreads();
    bf16x8 af[4], bfv[4];
    #pragma unroll
    for (int i = 0; i < 4; i++){
      int ra = wm * 64 + i * 16 + (lane & 15);
      af[i] = *(const bf16x8*)(As + ra * 32 + (lane >> 4) * 8);
      int rb = wn * 64 + i * 16 + (lane & 15);
      bfv[i] = *(const bf16x8*)(Bs + rb * 32 + (lane >> 4) * 8);
    }
    #pragma unroll
    for (int i = 0; i < 4; i++)
      #pragma unroll
      for (int j = 0; j < 4; j++)
        acc[i][j] = __builtin_amdgcn_mfma_f32_16x16x32_bf16(af[i], bfv[j], acc[i][j], 0, 0, 0);
    __syncthreads();
  }
  #pragma unroll
  for (int j = 0; j < 4; j++){
    int ncol = n0 + wn * 64 + j * 16 + (lane & 15);
    float bv = bias[ncol];
    #pragma unroll
    for (int i = 0; i < 4; i++){
      int mbase = m0 + wm * 64 + i * 16 + (lane >> 4) * 4;
      #pragma unroll
      for (int r = 0; r < 4; r++)
        gx[(size_t)(mbase + r) * G4 + ncol] = (unsigned short)f2bf(acc[i][j][r] + bv);
    }
  }
}

// ---------------- recur2 ----------------
// grid = 16 blocks x 512 threads. bid: grp = bid>>3 (batch group), g = bid&7 (h slice).
// h_hist [SS][NG][GS][NB][HSL] bf16 -> accessed ONLY via relaxed agent dword atomics.
// c_hist [16 blocks][SS][NB][HSL] f32 -> block-private, normal cached access.
// tags  [NG*GS] u32 monotonic step counters (memset 0 per launch).
__global__ __launch_bounds__(512, 2) void recur2(
    const int* __restrict__ prev_idx, const float* __restrict__ prev_w,
    const float* __restrict__ Whh, const int* __restrict__ positions,
    const unsigned short* __restrict__ gx,
    unsigned short* __restrict__ h_hist, float* __restrict__ c_hist,
    float* __restrict__ pooled, unsigned int* __restrict__ tags)
{
  __shared__ __align__(16) unsigned char hA[16 * 1024];  // h~ [16b][512] bf16, XOR-swizzled
  __shared__ float gex[NB][264];                         // recurrent gate partials (pad->conflict-free)
  __shared__ float wst[NB * 3];
  __shared__ int   ist[NB * 3];

  const int tid = threadIdx.x;
  const int lane = tid & 63, w = tid >> 6;
  const int bid = blockIdx.x, grp = bid >> 3, g = bid & 7;

  // ---- persistent B-fragments: Whh slice rows {q*512 + g*64 + [0,64)} ----
  bf16x8 bfr0[16], bfr1[16];
  #pragma unroll
  for (int kf = 0; kf < 16; kf++){
    #pragma unroll
    for (int i = 0; i < 2; i++){
      int nt = 2 * w + i;
      int grow = (nt >> 2) * HH + g * HSL + ((nt & 3) << 4) + (lane & 15);
      int kcol = kf * 32 + ((lane >> 4) << 3);
      const float* p = Whh + (size_t)grow * HH + kcol;
      float4 v0 = *(const float4*)p;
      float4 v1 = *(const float4*)(p + 4);
      bf16x8 tf;
      tf[0] = (short)f2bf(v0.x); tf[1] = (short)f2bf(v0.y);
      tf[2] = (short)f2bf(v0.z); tf[3] = (short)f2bf(v0.w);
      tf[4] = (short)f2bf(v1.x); tf[5] = (short)f2bf(v1.y);
      tf[6] = (short)f2bf(v1.z); tf[7] = (short)f2bf(v1.w);
      if (i == 0) bfr0[kf] = tf; else bfr1[kf] = tf;
    }
  }

  // elementwise mapping: 2 cells per thread
  const int cb = tid >> 5;             // local batch
  const int jd = (tid & 31) << 1;      // dim pair within slice
  const int bg = grp * NB + cb;
  const int st = positions[bg * 2], en = positions[bg * 2 + 1];
  float pm0 = -1e30f, pm1 = -1e30f;

  // gather mapping: batch-major in lanes for conflict-free LDS writes
  const int gq = tid & 15;             // batch
  const int gd = tid >> 4;             // 0..31 : 16-dim chunk of full 512
  const int ggs = gd >> 2;             // peer slice
  const int gdof = (gd & 3) << 4;      // dim offset in slice

  const size_t cblk = (size_t)bid * (SS * NB * HSL);
  unsigned int* hb = (unsigned int*)h_hist;

  for (int t = 0; t < SS; t++){
    if (t > 0){
      if (tid < NB * 3){
        int b = tid / 3, k = tid - b * 3;
        ist[tid] = prev_idx[(size_t)(grp * NB + b) * (SS * KKK) + t * KKK + k];
        wst[tid] = prev_w [(size_t)(grp * NB + b) * (SS * KKK) + t * KKK + k];
      }
      if (tid < GS){
        while (__hip_atomic_load(&tags[grp * GS + tid], __ATOMIC_RELAXED,
                                 __HIP_MEMORY_SCOPE_AGENT) < (unsigned)t)
          __builtin_amdgcn_s_sleep(1);
      }
      __syncthreads();

      { // gather h~ from LLC, weight, pack -> hA
        float w0 = wst[gq * 3], w1 = wst[gq * 3 + 1], w2 = wst[gq * 3 + 2];
        size_t s0 = ((((size_t)ist[gq*3  ] * NG + grp) * GS + ggs) * NB + gq) * HSL + gdof;
        size_t s1 = ((((size_t)ist[gq*3+1] * NG + grp) * GS + ggs) * NB + gq) * HSL + gdof;
        size_t s2 = ((((size_t)ist[gq*3+2] * NG + grp) * GS + ggs) * NB + gq) * HSL + gdof;
        s0 >>= 1; s1 >>= 1; s2 >>= 1;
        unsigned int dv0[8], dv1[8], dv2[8];
        #pragma unroll
        for (int j = 0; j < 8; j++)
          dv0[j] = __hip_atomic_load(hb + s0 + j, __ATOMIC_RELAXED, __HIP_MEMORY_SCOPE_AGENT);
        #pragma unroll
        for (int j = 0; j < 8; j++)
          dv1[j] = __hip_atomic_load(hb + s1 + j, __ATOMIC_RELAXED, __HIP_MEMORY_SCOPE_AGENT);
        #pragma unroll
        for (int j = 0; j < 8; j++)
          dv2[j] = __hip_atomic_load(hb + s2 + j, __ATOMIC_RELAXED, __HIP_MEMORY_SCOPE_AGENT);
        unsigned int pk[8];
        #pragma unroll
        for (int j = 0; j < 8; j++){
          float lo = w0 * blo(dv0[j]) + w1 * blo(dv1[j]) + w2 * blo(dv2[j]);
          float hi = w0 * bhi(dv0[j]) + w1 * bhi(dv1[j]) + w2 * bhi(dv2[j]);
          pk[j] = f2bf(lo) | (f2bf(hi) << 16);
        }
        int ob = (gq << 10) + gd * 32;
        int xr = (gq & 7) << 4;
        *(uint4*)(hA + (ob ^ xr))        = (uint4){pk[0], pk[1], pk[2], pk[3]};
        *(uint4*)(hA + ((ob + 16) ^ xr)) = (uint4){pk[4], pk[5], pk[6], pk[7]};
      }
      __syncthreads();

      { // MFMA: wave w -> n-tiles 2w, 2w+1 (32 gate rows), A = h~ (16 batches)
        f32x4 p00 = {0,0,0,0}, p01 = {0,0,0,0}, p10 = {0,0,0,0}, p11 = {0,0,0,0};
        const int rA = lane & 15;
        const int kb = (lane >> 4) << 4;
        const int xr = (rA & 7) << 4;
        const int rbase = rA << 10;
        #pragma unroll
        for (int kf = 0; kf < 16; kf += 2){
          bf16x8 a0 = *(const bf16x8*)(hA + ((rbase + kf * 64 + kb) ^ xr));
          bf16x8 a1 = *(const bf16x8*)(hA + ((rbase + (kf + 1) * 64 + kb) ^ xr));
          p00 = __builtin_amdgcn_mfma_f32_16x16x32_bf16(a0, bfr0[kf],     p00, 0, 0, 0);
          p10 = __builtin_amdgcn_mfma_f32_16x16x32_bf16(a0, bfr1[kf],     p10, 0, 0, 0);
          p01 = __builtin_amdgcn_mfma_f32_16x16x32_bf16(a1, bfr0[kf + 1], p01, 0, 0, 0);
          p11 = __builtin_amdgcn_mfma_f32_16x16x32_bf16(a1, bfr1[kf + 1], p11, 0, 0, 0);
        }
        int cl0 = (2 * w) * 16 + rA, cl1 = cl0 + 16;
        #pragma unroll
        for (int j = 0; j < 4; j++){
          int bq = ((lane >> 4) << 2) + j;
          gex[bq][cl0] = p00[j] + p01[j];
          gex[bq][cl1] = p10[j] + p11[j];
        }
      }
    }
    __syncthreads();

    { // elementwise LSTM cell: 2 cells (bg, g*64 + jd, jd+1)
      const unsigned short* rowb = gx + ((size_t)t * BB + bg) * G4 + g * HSL + jd;
      float g_i0 = bfu(rowb[0]),    g_i1 = bfu(rowb[1]);
      float g_f0 = bfu(rowb[512]),  g_f1 = bfu(rowb[513]);
      float g_g0 = bfu(rowb[1024]), g_g1 = bfu(rowb[1025]);
      float g_o0 = bfu(rowb[1536]), g_o1 = bfu(rowb[1537]);
      float co0 = 0.f, co1 = 0.f;
      if (t > 0){
        g_i0 += gex[cb][jd];        g_i1 += gex[cb][jd + 1];
        g_f0 += gex[cb][64 + jd];   g_f1 += gex[cb][64 + jd + 1];
        g_g0 += gex[cb][128 + jd];  g_g1 += gex[cb][128 + jd + 1];
        g_o0 += gex[cb][192 + jd];  g_o1 += gex[cb][192 + jd + 1];
        float w0 = wst[cb * 3], w1 = wst[cb * 3 + 1], w2 = wst[cb * 3 + 2];
        const float* cbase = c_hist + cblk + (size_t)cb * HSL + jd;
        size_t i0 = (size_t)ist[cb * 3]     * (NB * HSL);
        size_t i1 = (size_t)ist[cb * 3 + 1] * (NB * HSL);
        size_t i2 = (size_t)ist[cb * 3 + 2] * (NB * HSL);
        co0 = w0 * cbase[i0]     + w1 * cbase[i1]     + w2 * cbase[i2];
        co1 = w0 * cbase[i0 + 1] + w1 * cbase[i1 + 1] + w2 * cbase[i2 + 1];
      }
      float cn0 = sigm(g_f0) * co0 + sigm(g_i0) * tanh_(g_g0);
      float cn1 = sigm(g_f1) * co1 + sigm(g_i1) * tanh_(g_g1);
      float hn0 = sigm(g_o0) * tanh_(cn0);
      float hn1 = sigm(g_o1) * tanh_(cn1);
      float* cw = c_hist + cblk + ((size_t)t * NB + cb) * HSL + jd;
      cw[0] = cn0; cw[1] = cn1;
      unsigned int hv = f2bf(hn0) | (f2bf(hn1) << 16);
      unsigned int* hp = hb + (((((size_t)t * NG + grp) * GS + g) * NB + cb) * HSL + jd) / 2;
      __hip_atomic_store(hp, hv, __ATOMIC_RELAXED, __HIP_MEMORY_SCOPE_AGENT);
      if (t >= st && t < en){ pm0 = fmaxf(pm0, hn0); pm1 = fmaxf(pm1, hn1); }
    }
    __syncthreads();   // compiler drains vmcnt(0) before s_barrier -> h stores at LLC
    if (tid == 0)
      __hip_atomic_store(&tags[grp * GS + g], (unsigned)(t + 1),
                         __ATOMIC_RELAXED, __HIP_MEMORY_SCOPE_AGENT);
  }

  pooled[(size_t)bg * HH + g * HSL + jd]     = (en > st && pm0 > -1e29f) ? pm0 : 0.f;
  pooled[(size_t)bg * HH + g * HSL + jd + 1] = (en > st && pm1 > -1e29f) ? pm1 : 0.f;
}

// ---------------- pool_lin ----------------
__global__ __launch_bounds__(128) void pool_lin(
    const float* __restrict__ pooled, const float* __restrict__ W_lin,
    const float* __restrict__ b_lin, float* __restrict__ out)
{
  __shared__ float p[HH];
  int b = blockIdx.x, tid = threadIdx.x;
  *(float4*)&p[tid * 4] = *(const float4*)&pooled[(size_t)b * HH + tid * 4];
  __syncthreads();
  float acc = b_lin[tid];
  const float* wr = W_lin + (size_t)tid * HH;
  #pragma unroll 8
  for (int h = 0; h < HH; h += 4){
    float4 w = *(const float4*)(wr + h);
    acc += w.x * p[h] + w.y * p[h+1] + w.z * p[h+2] + w.w * p[h+3];
  }
  out[b * LL + tid] = acc;
}

extern "C" void kernel_launch(void* const* d_in, const int* in_sizes, int n_in,
                              void* d_out, int out_size, void* d_ws, size_t ws_size,
                              hipStream_t stream)
{
  (void)in_sizes; (void)n_in; (void)out_size; (void)ws_size;
  const int*   inputs    = (const int*)  d_in[0];
  const int*   positions = (const int*)  d_in[1];
  const int*   prev_idx  = (const int*)  d_in[2];
  const float* prev_w    = (const float*)d_in[3];
  const float* emb       = (const float*)d_in[4];
  const float* Wih       = (const float*)d_in[5];
  const float* Whh       = (const float*)d_in[6];
  const float* bih       = (const float*)d_in[7];
  const float* bhh       = (const float*)d_in[8];
  const float* W_lin     = (const float*)d_in[9];
  const float* b_lin     = (const float*)d_in[10];
  float* out = (float*)d_out;
  char* ws = (char*)d_ws;

  unsigned int*   tags   = (unsigned int*)  ws;                 // 64 B used
  unsigned short* Xb     = (unsigned short*)(ws + 4096);        // 8 MB
  unsigned short* Wihb   = (unsigned short*)(ws + 8392704);     // 2 MB
  float*          bias   = (float*)         (ws + 10489856);    // 8 KB
  unsigned short* gx     = (unsigned short*)(ws + 10498048);    // 32 MB
  unsigned short* h_hist = (unsigned short*)(ws + 44052480);    // 8 MB  [S][NG][GS][NB][HSL]
  float*          c_hist = (float*)         (ws + 52441088);    // 16 MB [16][S][NB][HSL]
  float*          pooled = (float*)         (ws + 69218304);    // 64 KB

  hipMemsetAsync(tags, 0, 4096, stream);
  prep_kernel<<<641, 256, 0, stream>>>(inputs, emb, Wih, bih, bhh, Xb, Wihb, bias);
  gemm_gx<<<dim3(64, 16), 256, 0, stream>>>(Xb, Wihb, bias, gx);
  recur2<<<16, 512, 0, stream>>>(prev_idx, prev_w, Whh, positions, gx, h_hist, c_hist, pooled, tags);
  pool_lin<<<32, 128, 0, stream>>>(pooled, W_lin, b_lin, out);
}

// Round 5
// 2260.439 us; speedup vs baseline: 1.1031x; 1.0147x over previous
//
#include <hip/hip_runtime.h>

// SLULatticeRNN: B=32, S=256, K=3, D=H=512, 4H=2048, L=128.
// recur5 = round-2 memory semantics (PROVEN: __hip_atomic relaxed/agent for h+tags,
// plain cached for block-private c and read-only gx) + three isolated fixes:
//   (a) launch_bounds(512,1): Whh fragments (128 VGPR) stay resident, no spill
//   (b) watermark slack-waiting: poll MALL tags only when cached lower bounds
//       don't cover max(prev_idx)+1 for the step
//   (c) checked prefetch: issue next step's h/c/gx loads at end of step ONLY
//       when the watermark already validates them (never speculative)

#define BB 32
#define SS 256
#define KKK 3
#define DD 512
#define HH 512
#define G4 2048
#define LL 128
#define NG 2    // batch groups
#define GS 8    // slice blocks per group
#define NB 16   // batches per group
#define HSL 64  // h dims per slice block

typedef __attribute__((ext_vector_type(4))) float f32x4;
typedef __attribute__((ext_vector_type(8))) short bf16x8;

__device__ __forceinline__ float blo(unsigned u){ return __builtin_bit_cast(float, u << 16); }
__device__ __forceinline__ float bhi(unsigned u){ return __builtin_bit_cast(float, u & 0xffff0000u); }
__device__ __forceinline__ unsigned f2bf(float f){
  unsigned x = __builtin_bit_cast(unsigned, f);
  x = x + 0x7fffu + ((x >> 16) & 1u);
  return x >> 16;
}
__device__ __forceinline__ float sigm(float x){ return 1.0f / (1.0f + __expf(-x)); }
__device__ __forceinline__ float tanh_(float x){
  float ax = fabsf(x);
  float e = __expf(-2.0f * ax);
  float r = (1.0f - e) / (1.0f + e);
  return x < 0.0f ? -r : r;
}
__device__ __forceinline__ void glds16(const void* g, void* lds){
  __builtin_amdgcn_global_load_lds((const __attribute__((address_space(1))) unsigned int*)g,
                                   (__attribute__((address_space(3))) unsigned int*)lds, 16, 0, 0);
}

// ---------------- prep: X gather->bf16, Wih->bf16, bias ----------------
__global__ __launch_bounds__(256) void prep_kernel(
    const int* __restrict__ inputs, const float* __restrict__ emb,
    const float* __restrict__ Wih, const float* __restrict__ bih, const float* __restrict__ bhh,
    unsigned short* __restrict__ Xb, unsigned short* __restrict__ Wihb, float* __restrict__ bias)
{
  int blk = blockIdx.x, tid = threadIdx.x;
  if (blk < 512){
    int row = blk * 16 + (tid >> 4);       // m = t*32+b
    int d0 = (tid & 15) * 32;
    int b = row & 31, t = row >> 5;
    int tok = inputs[b * SS + t];
    const float* src = emb + (size_t)tok * DD + d0;
    unsigned short* dst = Xb + (size_t)row * DD + d0;
    #pragma unroll
    for (int j = 0; j < 32; j += 4){
      float4 v = *(const float4*)(src + j);
      uint2 o;
      o.x = f2bf(v.x) | (f2bf(v.y) << 16);
      o.y = f2bf(v.z) | (f2bf(v.w) << 16);
      *(uint2*)(dst + j) = o;
    }
  } else if (blk < 640){
    int row = (blk - 512) * 16 + (tid >> 4);
    int d0 = (tid & 15) * 32;
    const float* src = Wih + (size_t)row * DD + d0;
    unsigned short* dst = Wihb + (size_t)row * DD + d0;
    #pragma unroll
    for (int j = 0; j < 32; j += 4){
      float4 v = *(const float4*)(src + j);
      uint2 o;
      o.x = f2bf(v.x) | (f2bf(v.y) << 16);
      o.y = f2bf(v.z) | (f2bf(v.w) << 16);
      *(uint2*)(dst + j) = o;
    }
  } else {
    for (int n = tid; n < G4; n += 256) bias[n] = bih[n] + bhh[n];
  }
}

// ---------------- gemm_gx: gates_x[m][n] = X[m]·Wih[n] + bias[n], bf16 out ----------------
__global__ __launch_bounds__(256) void gemm_gx(
    const unsigned short* __restrict__ Xb, const unsigned short* __restrict__ Wihb,
    const float* __restrict__ bias, unsigned short* __restrict__ gx)
{
  __shared__ unsigned short As[128 * 32];
  __shared__ unsigned short Bs[128 * 32];
  const int tid = threadIdx.x;
  const int lane = tid & 63, wid = tid >> 6;
  const int m0 = blockIdx.x * 128, n0 = blockIdx.y * 128;
  const int wm = wid & 1, wn = wid >> 1;
  f32x4 acc[4][4];
  #pragma unroll
  for (int i = 0; i < 4; i++)
    #pragma unroll
    for (int j = 0; j < 4; j++)
      acc[i][j] = (f32x4){0.f, 0.f, 0.f, 0.f};

  for (int kk = 0; kk < DD; kk += 32){
    #pragma unroll
    for (int r = 0; r < 2; r++){
      int q = r * 256 + wid * 64 + lane;
      int row = q >> 2, seg = q & 3;
      glds16(Xb   + (size_t)(m0 + row) * DD + kk + seg * 8, As + (size_t)(r * 256 + wid * 64) * 8);
      glds16(Wihb + (size_t)(n0 + row) * DD + kk + seg * 8, Bs + (size_t)(r * 256 + wid * 64) * 8);
    }
    __syncthreads();
    bf16x8 af[4], bfv[4];
    #pragma unroll
    for (int i = 0; i < 4; i++){
      int ra = wm * 64 + i * 16 + (lane & 15);
      af[i] = *(const bf16x8*)(As + ra * 32 + (lane >> 4) * 8);
      int rb = wn * 64 + i * 16 + (lane & 15);
      bfv[i] = *(const bf16x8*)(Bs + rb * 32 + (lane >> 4) * 8);
    }
    #pragma unroll
    for (int i = 0; i < 4; i++)
      #pragma unroll
      for (int j = 0; j < 4; j++)
        acc[i][j] = __builtin_amdgcn_mfma_f32_16x16x32_bf16(af[i], bfv[j], acc[i][j], 0, 0, 0);
    __syncthreads();
  }
  #pragma unroll
  for (int j = 0; j < 4; j++){
    int ncol = n0 + wn * 64 + j * 16 + (lane & 15);
    float bv = bias[ncol];
    #pragma unroll
    for (int i = 0; i < 4; i++){
      int mbase = m0 + wm * 64 + i * 16 + (lane >> 4) * 4;
      #pragma unroll
      for (int r = 0; r < 4; r++)
        gx[(size_t)(mbase + r) * G4 + ncol] = (unsigned short)f2bf(acc[i][j][r] + bv);
    }
  }
}

// ---------------- recur5 ----------------
// grid = 16 x 512. grp = bid>>3 (16 batches), g = bid&7 (64-dim h slice).
// h_hist [SS][NG][GS][NB][HSL] bf16: relaxed agent atomics only (round-2 proven).
// c_hist [16][SS][NB][HSL] f32: block-private, plain cached.
// tags[16]: monotonic published-step counters, relaxed agent atomics.
__global__ __launch_bounds__(512, 1) void recur5(
    const int* __restrict__ prev_idx, const float* __restrict__ prev_w,
    const float* __restrict__ Whh, const int* __restrict__ positions,
    const unsigned short* __restrict__ gx,
    unsigned short* __restrict__ h_hist, float* __restrict__ c_hist,
    float* __restrict__ pooled, unsigned int* __restrict__ tags)
{
  __shared__ __align__(16) unsigned char hA[16 * 1024];  // h~ [16b][512] bf16, XOR-swizzled
  __shared__ float gex[NB][264];
  __shared__ float wst2[2][NB * 3];
  __shared__ int   ist2[2][NB * 3];
  __shared__ int   wm_l[GS];          // cached lower bounds of peer tags
  __shared__ int   mneed2[2];         // max prev_idx per step slot
  __shared__ int   flag_s;            // 1 = prefetch for next step was issued & valid

  const int tid = threadIdx.x;
  const int lane = tid & 63, w = tid >> 6;
  const int bid = blockIdx.x, grp = bid >> 3, g = bid & 7;

  // ---- persistent B-fragments: Whh rows {q*512 + g*64 + [0,64)} (round-2 verbatim) ----
  bf16x8 bfr0[16], bfr1[16];
  #pragma unroll
  for (int kf = 0; kf < 16; kf++){
    #pragma unroll
    for (int i = 0; i < 2; i++){
      int nt = 2 * w + i;
      int grow = (nt >> 2) * HH + g * HSL + ((nt & 3) << 4) + (lane & 15);
      int kcol = kf * 32 + ((lane >> 4) << 3);
      const float* p = Whh + (size_t)grow * HH + kcol;
      float4 v0 = *(const float4*)p;
      float4 v1 = *(const float4*)(p + 4);
      bf16x8 tf;
      tf[0] = (short)f2bf(v0.x); tf[1] = (short)f2bf(v0.y);
      tf[2] = (short)f2bf(v0.z); tf[3] = (short)f2bf(v0.w);
      tf[4] = (short)f2bf(v1.x); tf[5] = (short)f2bf(v1.y);
      tf[6] = (short)f2bf(v1.z); tf[7] = (short)f2bf(v1.w);
      if (i == 0) bfr0[kf] = tf; else bfr1[kf] = tf;
    }
  }

  // mappings
  const int cb = tid >> 5;             // local batch (elementwise)
  const int jd = (tid & 31) << 1;      // dim pair within slice
  const int bg = grp * NB + cb;
  const int gq = tid & 15;             // batch (gather)
  const int gd = tid >> 4;             // 16-dim chunk of 512
  const int ggs = gd >> 2;             // peer slice
  const int gdof = (gd & 3) << 4;      // dim offset in slice

  const int st = positions[bg * 2], en = positions[bg * 2 + 1];
  float pm0 = -1e30f, pm1 = -1e30f;
  const size_t cblk = (size_t)bid * ((size_t)SS * NB * HSL);
  const unsigned* hb = (const unsigned*)h_hist;
  unsigned* hbw = (unsigned*)h_hist;

  // prefetch registers (all statically indexed after unroll)
  unsigned dv0[8], dv1[8], dv2[8];
  float2 cg0, cg1, cg2;
  unsigned gxv0, gxv1, gxv2, gxv3;

  if (tid < GS) wm_l[tid] = 0;
  __syncthreads();

  auto issue_gather = [&](int slot){
    int i0 = ist2[slot][gq * 3], i1 = ist2[slot][gq * 3 + 1], i2 = ist2[slot][gq * 3 + 2];
    size_t s0 = (((((size_t)i0 * NG + grp) * GS + ggs) * NB + gq) * HSL + gdof) >> 1;
    size_t s1 = (((((size_t)i1 * NG + grp) * GS + ggs) * NB + gq) * HSL + gdof) >> 1;
    size_t s2 = (((((size_t)i2 * NG + grp) * GS + ggs) * NB + gq) * HSL + gdof) >> 1;
    #pragma unroll
    for (int j = 0; j < 8; j++)
      dv0[j] = __hip_atomic_load(hb + s0 + j, __ATOMIC_RELAXED, __HIP_MEMORY_SCOPE_AGENT);
    #pragma unroll
    for (int j = 0; j < 8; j++)
      dv1[j] = __hip_atomic_load(hb + s1 + j, __ATOMIC_RELAXED, __HIP_MEMORY_SCOPE_AGENT);
    #pragma unroll
    for (int j = 0; j < 8; j++)
      dv2[j] = __hip_atomic_load(hb + s2 + j, __ATOMIC_RELAXED, __HIP_MEMORY_SCOPE_AGENT);
  };
  auto issue_cgx = [&](int slot, int tn){
    const float* cb0 = c_hist + cblk + (size_t)cb * HSL + jd;
    cg0 = *(const float2*)(cb0 + (size_t)ist2[slot][cb * 3]     * (NB * HSL));
    cg1 = *(const float2*)(cb0 + (size_t)ist2[slot][cb * 3 + 1] * (NB * HSL));
    cg2 = *(const float2*)(cb0 + (size_t)ist2[slot][cb * 3 + 2] * (NB * HSL));
    const unsigned short* gxr = gx + ((size_t)tn * BB + bg) * G4 + g * HSL + jd;
    gxv0 = *(const unsigned*)(gxr);
    gxv1 = *(const unsigned*)(gxr + 512);
    gxv2 = *(const unsigned*)(gxr + 1024);
    gxv3 = *(const unsigned*)(gxr + 1536);
  };

  // ---------------- t = 0 prologue ----------------
  {
    const unsigned short* gxr = gx + (size_t)bg * G4 + g * HSL + jd;
    gxv0 = *(const unsigned*)(gxr);
    gxv1 = *(const unsigned*)(gxr + 512);
    gxv2 = *(const unsigned*)(gxr + 1024);
    gxv3 = *(const unsigned*)(gxr + 1536);
    int iv = -1;
    if (tid < NB * 3){
      int b = tid / 3, k = tid - b * 3;
      iv = prev_idx[(size_t)(grp * NB + b) * (SS * KKK) + 1 * KKK + k];
      ist2[1][tid] = iv;
      wst2[1][tid] = prev_w[(size_t)(grp * NB + b) * (SS * KKK) + 1 * KKK + k];
    }
    if (tid < 64){
      int m = iv;
      #pragma unroll
      for (int off = 32; off; off >>= 1) m = max(m, __shfl_xor(m, off));
      if (tid == 0) mneed2[1] = m;
    }
    float cn0 = sigm(blo(gxv0)) * tanh_(blo(gxv2));
    float cn1 = sigm(bhi(gxv0)) * tanh_(bhi(gxv2));
    float hn0 = sigm(blo(gxv3)) * tanh_(cn0);
    float hn1 = sigm(bhi(gxv3)) * tanh_(cn1);
    *(float2*)(c_hist + cblk + (size_t)cb * HSL + jd) = make_float2(cn0, cn1);
    unsigned hv = f2bf(hn0) | (f2bf(hn1) << 16);
    __hip_atomic_store(hbw + (((((size_t)grp * GS + g) * NB + cb) * HSL + jd) >> 1), hv,
                       __ATOMIC_RELAXED, __HIP_MEMORY_SCOPE_AGENT);
    if (0 >= st && 0 < en){ pm0 = fmaxf(pm0, hn0); pm1 = fmaxf(pm1, hn1); }
    __syncthreads();   // drains h/c stores; publishes ist2[1]/mneed2[1] block-wide
    if (tid == 0){
      __hip_atomic_store(&tags[grp * GS + g], 1u, __ATOMIC_RELAXED, __HIP_MEMORY_SCOPE_AGENT);
      wm_l[g] = 1;
      int m = wm_l[0];
      #pragma unroll
      for (int p = 1; p < GS; p++) m = min(m, wm_l[p]);
      flag_s = (m >= mneed2[1] + 1) ? 1 : 0;
    }
    __syncthreads();
  }
  bool valid = (flag_s != 0);
  if (valid) issue_gather(1);
  issue_cgx(1, 1);

  // ---------------- main loop ----------------
  for (int t = 1; t < SS; t++){
    const int sl = t & 1, sn = sl ^ 1;

    // [A] poll only when prefetch wasn't validated
    if (!valid){
      const int need = mneed2[sl] + 1;
      if (tid < GS){
        int v = wm_l[tid];
        if (v < need){
          const unsigned int* tp = tags + grp * GS + tid;
          do {
            v = (int)__hip_atomic_load(tp, __ATOMIC_RELAXED, __HIP_MEMORY_SCOPE_AGENT);
            if (v < need) __builtin_amdgcn_s_sleep(1);
          } while (v < need);
          wm_l[tid] = v;
        }
      }
      __syncthreads();
      issue_gather(sl);
    }

    // [B] weight + pack h~ -> hA (XOR-swizzled)
    {
      float w0 = wst2[sl][gq * 3], w1 = wst2[sl][gq * 3 + 1], w2 = wst2[sl][gq * 3 + 2];
      unsigned pk[8];
      #pragma unroll
      for (int j = 0; j < 8; j++){
        float lo = w0 * blo(dv0[j]) + w1 * blo(dv1[j]) + w2 * blo(dv2[j]);
        float hi = w0 * bhi(dv0[j]) + w1 * bhi(dv1[j]) + w2 * bhi(dv2[j]);
        pk[j] = f2bf(lo) | (f2bf(hi) << 16);
      }
      int ob = (gq << 10) + gd * 32;
      int xr = (gq & 7) << 4;
      *(uint4*)(hA + (ob ^ xr))        = (uint4){pk[0], pk[1], pk[2], pk[3]};
      *(uint4*)(hA + ((ob + 16) ^ xr)) = (uint4){pk[4], pk[5], pk[6], pk[7]};
    }
    __syncthreads();

    // [C] load ist/wst(t+1) (overlaps MFMA) ; MFMA: wave w -> gate cols [32w,32w+32)
    int iv = -1;
    if (t + 1 < SS){
      if (tid < NB * 3){
        int b = tid / 3, k = tid - b * 3;
        iv = prev_idx[(size_t)(grp * NB + b) * (SS * KKK) + (t + 1) * KKK + k];
        ist2[sn][tid] = iv;
        wst2[sn][tid] = prev_w[(size_t)(grp * NB + b) * (SS * KKK) + (t + 1) * KKK + k];
      }
    }
    {
      f32x4 p00 = {0,0,0,0}, p01 = {0,0,0,0}, p10 = {0,0,0,0}, p11 = {0,0,0,0};
      const int rA = lane & 15;
      const int kb = (lane >> 4) << 4;
      const int xr = (rA & 7) << 4;
      const int rbase = rA << 10;
      #pragma unroll
      for (int kf = 0; kf < 16; kf += 2){
        bf16x8 a0 = *(const bf16x8*)(hA + ((rbase + kf * 64 + kb) ^ xr));
        bf16x8 a1 = *(const bf16x8*)(hA + ((rbase + (kf + 1) * 64 + kb) ^ xr));
        p00 = __builtin_amdgcn_mfma_f32_16x16x32_bf16(a0, bfr0[kf],     p00, 0, 0, 0);
        p10 = __builtin_amdgcn_mfma_f32_16x16x32_bf16(a0, bfr1[kf],     p10, 0, 0, 0);
        p01 = __builtin_amdgcn_mfma_f32_16x16x32_bf16(a1, bfr0[kf + 1], p01, 0, 0, 0);
        p11 = __builtin_amdgcn_mfma_f32_16x16x32_bf16(a1, bfr1[kf + 1], p11, 0, 0, 0);
      }
      int cl0 = (2 * w) * 16 + rA, cl1 = cl0 + 16;
      #pragma unroll
      for (int j = 0; j < 4; j++){
        int bq = ((lane >> 4) << 2) + j;
        gex[bq][cl0] = p00[j] + p01[j];
        gex[bq][cl1] = p10[j] + p11[j];
      }
    }
    if (t + 1 < SS && tid < 64){
      int m = iv;
      #pragma unroll
      for (int off = 32; off; off >>= 1) m = max(m, __shfl_xor(m, off));
      if (tid == 0) mneed2[sn] = m;
    }
    __syncthreads();

    // [D] elementwise LSTM cell (gex LDS + prefetched gx/c regs) + stores
    {
      float w0 = wst2[sl][cb * 3], w1 = wst2[sl][cb * 3 + 1], w2 = wst2[sl][cb * 3 + 2];
      float g_i0 = blo(gxv0) + gex[cb][jd];
      float g_i1 = bhi(gxv0) + gex[cb][jd + 1];
      float g_f0 = blo(gxv1) + gex[cb][64 + jd];
      float g_f1 = bhi(gxv1) + gex[cb][64 + jd + 1];
      float g_g0 = blo(gxv2) + gex[cb][128 + jd];
      float g_g1 = bhi(gxv2) + gex[cb][128 + jd + 1];
      float g_o0 = blo(gxv3) + gex[cb][192 + jd];
      float g_o1 = bhi(gxv3) + gex[cb][192 + jd + 1];
      float co0 = w0 * cg0.x + w1 * cg1.x + w2 * cg2.x;
      float co1 = w0 * cg0.y + w1 * cg1.y + w2 * cg2.y;
      float cn0 = sigm(g_f0) * co0 + sigm(g_i0) * tanh_(g_g0);
      float cn1 = sigm(g_f1) * co1 + sigm(g_i1) * tanh_(g_g1);
      float hn0 = sigm(g_o0) * tanh_(cn0);
      float hn1 = sigm(g_o1) * tanh_(cn1);
      *(float2*)(c_hist + cblk + ((size_t)t * NB + cb) * HSL + jd) = make_float2(cn0, cn1);
      unsigned hv = f2bf(hn0) | (f2bf(hn1) << 16);
      __hip_atomic_store(hbw + ((((((size_t)t * NG + grp) * GS + g) * NB + cb) * HSL + jd) >> 1),
                         hv, __ATOMIC_RELAXED, __HIP_MEMORY_SCOPE_AGENT);
      if (t >= st && t < en){ pm0 = fmaxf(pm0, hn0); pm1 = fmaxf(pm1, hn1); }
    }
    __syncthreads();   // compiler drains vmcnt(0) -> h/c stores visible before tag

    // [E] publish + prefetch decision + (validated) prefetch issue
    if (tid == 0){
      __hip_atomic_store(&tags[grp * GS + g], (unsigned)(t + 1),
                         __ATOMIC_RELAXED, __HIP_MEMORY_SCOPE_AGENT);
      wm_l[g] = t + 1;
      int f = 0;
      if (t + 1 < SS){
        int m = wm_l[0];
        #pragma unroll
        for (int p = 1; p < GS; p++) m = min(m, wm_l[p]);
        f = (m >= mneed2[sn] + 1) ? 1 : 0;
      }
      flag_s = f;
    }
    __syncthreads();
    valid = (flag_s != 0);
    if (t + 1 < SS){
      if (valid) issue_gather(sn);   // only issued when watermark-validated
      issue_cgx(sn, t + 1);          // own-block data: always safe
    }
  }

  pooled[(size_t)bg * HH + g * HSL + jd]     = (en > st && pm0 > -1e29f) ? pm0 : 0.f;
  pooled[(size_t)bg * HH + g * HSL + jd + 1] = (en > st && pm1 > -1e29f) ? pm1 : 0.f;
}

// ---------------- pool_lin ----------------
__global__ __launch_bounds__(128) void pool_lin(
    const float* __restrict__ pooled, const float* __restrict__ W_lin,
    const float* __restrict__ b_lin, float* __restrict__ out)
{
  __shared__ float p[HH];
  int b = blockIdx.x, tid = threadIdx.x;
  *(float4*)&p[tid * 4] = *(const float4*)&pooled[(size_t)b * HH + tid * 4];
  __syncthreads();
  float acc = b_lin[tid];
  const float* wr = W_lin + (size_t)tid * HH;
  #pragma unroll 8
  for (int h = 0; h < HH; h += 4){
    float4 w = *(const float4*)(wr + h);
    acc += w.x * p[h] + w.y * p[h+1] + w.z * p[h+2] + w.w * p[h+3];
  }
  out[b * LL + tid] = acc;
}

extern "C" void kernel_launch(void* const* d_in, const int* in_sizes, int n_in,
                              void* d_out, int out_size, void* d_ws, size_t ws_size,
                              hipStream_t stream)
{
  (void)in_sizes; (void)n_in; (void)out_size; (void)ws_size;
  const int*   inputs    = (const int*)  d_in[0];
  const int*   positions = (const int*)  d_in[1];
  const int*   prev_idx  = (const int*)  d_in[2];
  const float* prev_w    = (const float*)d_in[3];
  const float* emb       = (const float*)d_in[4];
  const float* Wih       = (const float*)d_in[5];
  const float* Whh       = (const float*)d_in[6];
  const float* bih       = (const float*)d_in[7];
  const float* bhh       = (const float*)d_in[8];
  const float* W_lin     = (const float*)d_in[9];
  const float* b_lin     = (const float*)d_in[10];
  float* out = (float*)d_out;
  char* ws = (char*)d_ws;

  unsigned int*   tags   = (unsigned int*)  ws;                 // 64 B
  unsigned short* Xb     = (unsigned short*)(ws + 4096);        // 8 MB
  unsigned short* Wihb   = (unsigned short*)(ws + 8392704);     // 2 MB
  float*          bias   = (float*)         (ws + 10489856);    // 8 KB
  unsigned short* gx     = (unsigned short*)(ws + 10498048);    // 32 MB
  unsigned short* h_hist = (unsigned short*)(ws + 44052480);    // 8 MB  [S][NG][GS][NB][HSL]
  float*          c_hist = (float*)         (ws + 52441088);    // 16 MB [16][S][NB][HSL]
  float*          pooled = (float*)         (ws + 69218304);    // 64 KB

  hipMemsetAsync(tags, 0, 4096, stream);
  prep_kernel<<<641, 256, 0, stream>>>(inputs, emb, Wih, bih, bhh, Xb, Wihb, bias);
  gemm_gx<<<dim3(64, 16), 256, 0, stream>>>(Xb, Wihb, bias, gx);
  recur5<<<16, 512, 0, stream>>>(prev_idx, prev_w, Whh, positions, gx, h_hist, c_hist, pooled, tags);
  pool_lin<<<32, 128, 0, stream>>>(pooled, W_lin, b_lin, out);
}